// Round 1
// baseline (1341.163 us; speedup 1.0000x reference)
//
#include <hip/hip_runtime.h>
#include <math.h>

#define N_PTS 8192
#define B_SZ 4
#define SEED_NUM 409
#define FPS_THREADS 1024
#define PTS_PER_THR (N_PTS / FPS_THREADS)  // 8
#define KMAX 196

// Exact IEEE f32 squared distance, same op order as the reference:
// ((dx*dx + dy*dy) + dz*dz), no FMA contraction.
__device__ __forceinline__ float sqdist(float ax, float ay, float az,
                                        float bx, float by, float bz) {
  float dx = __fsub_rn(ax, bx);
  float dy = __fsub_rn(ay, by);
  float dz = __fsub_rn(az, bz);
  return __fadd_rn(__fadd_rn(__fmul_rn(dx, dx), __fmul_rn(dy, dy)),
                   __fmul_rn(dz, dz));
}

// ---------------------------------------------------------------------------
// Kernel 1: farthest point sampling. One block per batch. Points live in
// registers (8/thread, strided i = tid + k*1024); min_d2 in registers.
// Per step: seed write, distance+min update, argmax (first-index tie-break,
// matching jnp.argmax), broadcast of winner coords via LDS.
// ---------------------------------------------------------------------------
__global__ __launch_bounds__(FPS_THREADS) void fps_kernel(
    const float* __restrict__ pcs, float* __restrict__ seeds) {
  const int b = blockIdx.x;
  const int tid = threadIdx.x;
  const float* base = pcs + (size_t)b * N_PTS * 3;

  float px[PTS_PER_THR], py[PTS_PER_THR], pz[PTS_PER_THR], md[PTS_PER_THR];
#pragma unroll
  for (int k = 0; k < PTS_PER_THR; ++k) {
    int i = tid + k * FPS_THREADS;
    px[k] = base[i * 3 + 0];
    py[k] = base[i * 3 + 1];
    pz[k] = base[i * 3 + 2];
    md[k] = 1e10f;  // reference init 10000000000.0 -> f32
  }

  __shared__ float red_v[16];
  __shared__ int red_i[16];
  __shared__ float curc[3];
  __shared__ int cur_i;

  // initial point: index 0 (owned by tid 0, k 0)
  if (tid == 0) { curc[0] = px[0]; curc[1] = py[0]; curc[2] = pz[0]; }
  __syncthreads();
  float cx = curc[0], cy = curc[1], cz = curc[2];

  for (int s = 0; s < SEED_NUM; ++s) {
    if (tid == 0) {
      float* sp = seeds + ((size_t)b * SEED_NUM + s) * 3;
      sp[0] = cx; sp[1] = cy; sp[2] = cz;
    }
    float bv = -1.0f;
    int bi = N_PTS;
#pragma unroll
    for (int k = 0; k < PTS_PER_THR; ++k) {
      float d2 = sqdist(px[k], py[k], pz[k], cx, cy, cz);
      float m = fminf(md[k], d2);
      md[k] = m;
      int i = tid + k * FPS_THREADS;
      if (m > bv || (m == bv && i < bi)) { bv = m; bi = i; }
    }
    // 64-lane wave reduce, first-index tie-break
#pragma unroll
    for (int off = 32; off > 0; off >>= 1) {
      float ov = __shfl_down(bv, off);
      int oi = __shfl_down(bi, off);
      if (ov > bv || (ov == bv && oi < bi)) { bv = ov; bi = oi; }
    }
    const int lane = tid & 63, wid = tid >> 6;
    if (lane == 0) { red_v[wid] = bv; red_i[wid] = bi; }
    __syncthreads();
    if (tid == 0) {
      float v = red_v[0];
      int i0 = red_i[0];
      for (int w = 1; w < 16; ++w) {
        if (red_v[w] > v || (red_v[w] == v && red_i[w] < i0)) {
          v = red_v[w]; i0 = red_i[w];
        }
      }
      cur_i = i0;
    }
    __syncthreads();
    const int ci = cur_i;
    if (tid == (ci & (FPS_THREADS - 1))) {
      const int k = ci >> 10;
      curc[0] = px[k]; curc[1] = py[k]; curc[2] = pz[k];
    }
    __syncthreads();
    cx = curc[0]; cy = curc[1]; cz = curc[2];
  }
}

// ---------------------------------------------------------------------------
// Kernel 2: per (group, percentage): ball query (first K valid in index
// order via ballot prefix-sum compaction into LDS) + count, then 2nd-NN
// within the group, clutter sum and imbalance/gnum accumulated via double
// atomics.
// ---------------------------------------------------------------------------
__global__ __launch_bounds__(256) void group_kernel(
    const float* __restrict__ pcs, const float* __restrict__ seeds,
    double* __restrict__ totS /*[5]*/, double* __restrict__ accA /*[5][4]*/) {
  const int g = blockIdx.x;  // 0 .. B*SEED_NUM-1
  const int p = blockIdx.y;  // 0 .. 4
  const int b = g / SEED_NUM;
  const int tid = threadIdx.x;
  const int lane = tid & 63, wid = tid >> 6;

  const double P[5] = {0.004, 0.006, 0.008, 0.01, 0.012};
  const double pd = P[p];
  const double rd = sqrt(pd);
  const float r2 = (float)(rd * rd);          // weak f32 cast of python r*r
  const double expn_d = 8192.0 * pd;          // exp_num (f64)
  const int K = (int)(2.0 * expn_d);          // 65, 98, 131, 163, 196
  const float expn_f = (float)expn_d;
  const float expect_dis = sqrtf((float)(M_PI / expn_d * pd));  // = sqrt(pi/N)

  const float* base = pcs + (size_t)b * N_PTS * 3;
  const float* sp = seeds + (size_t)g * 3;
  const float sx = sp[0], sy = sp[1], sz = sp[2];

  __shared__ float gx[KMAX], gy[KMAX], gz[KMAX];
  __shared__ int wtot[4];
  __shared__ double wsum[4];

  int run = 0;  // running valid count (uniform across block)
  for (int base_i = 0; base_i < N_PTS; base_i += 256) {
    const int i = base_i + tid;
    const float x = base[i * 3 + 0];
    const float y = base[i * 3 + 1];
    const float z = base[i * 3 + 2];
    const float d2 = sqdist(x, y, z, sx, sy, sz);
    const bool valid = d2 < r2;
    const unsigned long long m = __ballot(valid);
    if (lane == 0) wtot[wid] = __popcll(m);
    __syncthreads();
    int pos = run + __popcll(m & ((1ull << lane) - 1ull));
    for (int w = 0; w < wid; ++w) pos += wtot[w];
    if (valid && pos < K) { gx[pos] = x; gy[pos] = y; gz[pos] = z; }
    run += wtot[0] + wtot[1] + wtot[2] + wtot[3];
    __syncthreads();  // protect wtot (and gx writes) before next chunk
  }
  const int gnum = run < K ? run : K;  // = min(cnt, K), >= 1 (seed is in pcs)

  // 2nd-smallest pairwise d2 per row (self-distance 0 included => nearest
  // neighbor). Exact-tie handling matches top_k-by-value.
  double localS = 0.0;
  if (tid < gnum) {
    const float xi = gx[tid], yi = gy[tid], zi = gz[tid];
    float m1 = INFINITY, m2 = INFINITY;
    for (int j = 0; j < gnum; ++j) {
      const float d2 = sqdist(xi, yi, zi, gx[j], gy[j], gz[j]);
      if (d2 < m1) { m2 = m1; m1 = d2; }
      else if (d2 < m2) { m2 = d2; }
    }
    const float nn2 = (m2 > 1e37f) ? 0.0f : m2;  // inf (gnum==1) -> 0
    const float nnd = (nn2 > 0.0f) ? sqrtf(nn2) : 0.0f;
    const float diff = __fsub_rn(nnd, expect_dis);
    const float clut = __fdiv_rn(__fmul_rn(diff, diff),
                                 __fadd_rn(expect_dis, 1e-12f));
    localS = (double)clut;
  }
#pragma unroll
  for (int off = 32; off > 0; off >>= 1) localS += __shfl_down(localS, off);
  if (lane == 0) wsum[wid] = localS;
  __syncthreads();
  if (tid == 0) {
    const double S = wsum[0] + wsum[1] + wsum[2] + wsum[3];
    atomicAdd(&totS[p], S);
    const float gf = (float)gnum;
    const float d = __fsub_rn(gf, expn_f);
    const float imb = __fdiv_rn(__fmul_rn(d, d), expn_f);
    atomicAdd(&accA[p * 4 + b], (double)imb / (double)gf);
  }
}

// ---------------------------------------------------------------------------
// Kernel 3: loss[b] = (1/5) * sum_p totS[p] * (accA[p][b] / 409)
// ---------------------------------------------------------------------------
__global__ void finalize_kernel(const double* __restrict__ totS,
                                const double* __restrict__ accA,
                                float* __restrict__ out) {
  const int b = threadIdx.x;
  if (b < B_SZ) {
    double acc = 0.0;
    for (int p = 0; p < 5; ++p)
      acc += totS[p] * (accA[p * 4 + b] / (double)SEED_NUM);
    out[b] = (float)(acc / 5.0);
  }
}

__global__ void zero_kernel(double* __restrict__ ptr) {
  const int t = threadIdx.x;
  if (t < 25) ptr[t] = 0.0;  // totS[5] + accA[20]
}

extern "C" void kernel_launch(void* const* d_in, const int* in_sizes, int n_in,
                              void* d_out, int out_size, void* d_ws,
                              size_t ws_size, hipStream_t stream) {
  (void)in_sizes; (void)n_in; (void)out_size; (void)ws_size;
  const float* pcs = (const float*)d_in[0];
  float* out = (float*)d_out;

  // ws layout: seeds (B*409*3 f32 = 19632 B, 8-aligned), then 25 doubles.
  float* seeds = (float*)d_ws;
  double* sums = (double*)((char*)d_ws + 19632);

  zero_kernel<<<1, 32, 0, stream>>>(sums);
  fps_kernel<<<B_SZ, FPS_THREADS, 0, stream>>>(pcs, seeds);
  dim3 grid(B_SZ * SEED_NUM, 5);
  group_kernel<<<grid, 256, 0, stream>>>(pcs, seeds, sums, sums + 5);
  finalize_kernel<<<1, 64, 0, stream>>>(sums, sums + 5, out);
}

// Round 2
// 658.077 us; speedup vs baseline: 2.0380x; 2.0380x over previous
//
#include <hip/hip_runtime.h>
#include <math.h>

#define N_PTS 8192
#define B_SZ 4
#define SEED_NUM 409
#define FPS_THREADS 512
#define PPT (N_PTS / FPS_THREADS)  // 16 points per thread
#define KMAX 196

// Exact IEEE f32 squared distance, same op order as the reference:
// ((dx*dx + dy*dy) + dz*dz), no FMA contraction.
__device__ __forceinline__ float sqdist(float ax, float ay, float az,
                                        float bx, float by, float bz) {
  float dx = __fsub_rn(ax, bx);
  float dy = __fsub_rn(ay, by);
  float dz = __fsub_rn(az, bz);
  return __fadd_rn(__fadd_rn(__fmul_rn(dx, dx), __fmul_rn(dy, dy)),
                   __fmul_rn(dz, dz));
}

// ---------------------------------------------------------------------------
// Kernel 1: farthest point sampling. One block per batch (4 blocks). Points
// live in registers (16/thread, strided i = tid + k*512, so index increases
// with k => strict '>' keeps the first index on ties within a thread).
// Argmax reduce uses a packed u64 key (value f32 bits << 32 | (8191 - idx)):
// values are >= 0 so float bits are monotone; u64 max == (max value, tie ->
// min index), exactly matching jnp.argmax. One barrier per step via a
// double-buffered partial array; winner coords come from a same-address
// (broadcast) global load, L1/L2 resident.
// ---------------------------------------------------------------------------
__global__ __launch_bounds__(FPS_THREADS, 1) void fps_kernel(
    const float* __restrict__ pcs, float* __restrict__ seeds) {
  const int b = blockIdx.x;
  const int tid = threadIdx.x;
  const int lane = tid & 63, wid = tid >> 6;  // 8 waves
  const float* base = pcs + (size_t)b * N_PTS * 3;

  float px[PPT], py[PPT], pz[PPT], md[PPT];
#pragma unroll
  for (int k = 0; k < PPT; ++k) {
    const int i = tid + k * FPS_THREADS;
    px[k] = base[i * 3 + 0];
    py[k] = base[i * 3 + 1];
    pz[k] = base[i * 3 + 2];
    md[k] = 1e10f;  // reference init 10000000000.0 -> f32 (exact)
  }

  __shared__ unsigned long long red[2][8];

  // initial point: index 0 (broadcast global read)
  float cx = base[0], cy = base[1], cz = base[2];

  for (int s = 0; s < SEED_NUM; ++s) {
    if (tid == 0) {
      float* sp = seeds + ((size_t)b * SEED_NUM + s) * 3;
      sp[0] = cx; sp[1] = cy; sp[2] = cz;
    }
    float bv = -1.0f;
    int bi = 0;
#pragma unroll
    for (int k = 0; k < PPT; ++k) {
      const float d2 = sqdist(px[k], py[k], pz[k], cx, cy, cz);
      const float m = fminf(md[k], d2);
      md[k] = m;
      if (m > bv) { bv = m; bi = tid + k * FPS_THREADS; }
    }
    unsigned long long key =
        ((unsigned long long)__float_as_uint(bv) << 32) |
        (unsigned long long)(unsigned)(N_PTS - 1 - bi);
#pragma unroll
    for (int off = 32; off > 0; off >>= 1) {
      const unsigned long long o = __shfl_down(key, off);
      key = (o > key) ? o : key;
    }
    if (lane == 0) red[s & 1][wid] = key;
    __syncthreads();
    unsigned long long kmax = red[s & 1][0];
#pragma unroll
    for (int w = 1; w < 8; ++w) {
      const unsigned long long o = red[s & 1][w];
      kmax = (o > kmax) ? o : kmax;
    }
    const int ci = N_PTS - 1 - (int)(unsigned)(kmax & 0xffffffffull);
    const float* cp = base + (size_t)ci * 3;
    cx = cp[0]; cy = cp[1]; cz = cp[2];
  }
}

// ---------------------------------------------------------------------------
// Kernel 2: per (group, percentage): ball query (first K valid in index
// order via ballot prefix-sum compaction into LDS) + count, then 2nd-NN
// within the group, clutter sum and imbalance/gnum accumulated via double
// atomics. (unchanged from round 1 — passed with absmax 0.0)
// ---------------------------------------------------------------------------
__global__ __launch_bounds__(256) void group_kernel(
    const float* __restrict__ pcs, const float* __restrict__ seeds,
    double* __restrict__ totS /*[5]*/, double* __restrict__ accA /*[5][4]*/) {
  const int g = blockIdx.x;  // 0 .. B*SEED_NUM-1
  const int p = blockIdx.y;  // 0 .. 4
  const int b = g / SEED_NUM;
  const int tid = threadIdx.x;
  const int lane = tid & 63, wid = tid >> 6;

  const double P[5] = {0.004, 0.006, 0.008, 0.01, 0.012};
  const double pd = P[p];
  const double rd = sqrt(pd);
  const float r2 = (float)(rd * rd);          // weak f32 cast of python r*r
  const double expn_d = 8192.0 * pd;          // exp_num (f64)
  const int K = (int)(2.0 * expn_d);          // 65, 98, 131, 163, 196
  const float expn_f = (float)expn_d;
  const float expect_dis = sqrtf((float)(M_PI / expn_d * pd));  // = sqrt(pi/N)

  const float* base = pcs + (size_t)b * N_PTS * 3;
  const float* sp = seeds + (size_t)g * 3;
  const float sx = sp[0], sy = sp[1], sz = sp[2];

  __shared__ float gx[KMAX], gy[KMAX], gz[KMAX];
  __shared__ int wtot[4];
  __shared__ double wsum[4];

  int run = 0;  // running valid count (uniform across block)
  for (int base_i = 0; base_i < N_PTS; base_i += 256) {
    const int i = base_i + tid;
    const float x = base[i * 3 + 0];
    const float y = base[i * 3 + 1];
    const float z = base[i * 3 + 2];
    const float d2 = sqdist(x, y, z, sx, sy, sz);
    const bool valid = d2 < r2;
    const unsigned long long m = __ballot(valid);
    if (lane == 0) wtot[wid] = __popcll(m);
    __syncthreads();
    int pos = run + __popcll(m & ((1ull << lane) - 1ull));
    for (int w = 0; w < wid; ++w) pos += wtot[w];
    if (valid && pos < K) { gx[pos] = x; gy[pos] = y; gz[pos] = z; }
    run += wtot[0] + wtot[1] + wtot[2] + wtot[3];
    __syncthreads();  // protect wtot (and gx writes) before next chunk
  }
  const int gnum = run < K ? run : K;  // = min(cnt, K), >= 1 (seed is in pcs)

  // 2nd-smallest pairwise d2 per row (self-distance 0 included => nearest
  // neighbor). Exact-tie handling matches top_k-by-value.
  double localS = 0.0;
  if (tid < gnum) {
    const float xi = gx[tid], yi = gy[tid], zi = gz[tid];
    float m1 = INFINITY, m2 = INFINITY;
    for (int j = 0; j < gnum; ++j) {
      const float d2 = sqdist(xi, yi, zi, gx[j], gy[j], gz[j]);
      if (d2 < m1) { m2 = m1; m1 = d2; }
      else if (d2 < m2) { m2 = d2; }
    }
    const float nn2 = (m2 > 1e37f) ? 0.0f : m2;  // inf (gnum==1) -> 0
    const float nnd = (nn2 > 0.0f) ? sqrtf(nn2) : 0.0f;
    const float diff = __fsub_rn(nnd, expect_dis);
    const float clut = __fdiv_rn(__fmul_rn(diff, diff),
                                 __fadd_rn(expect_dis, 1e-12f));
    localS = (double)clut;
  }
#pragma unroll
  for (int off = 32; off > 0; off >>= 1) localS += __shfl_down(localS, off);
  if (lane == 0) wsum[wid] = localS;
  __syncthreads();
  if (tid == 0) {
    const double S = wsum[0] + wsum[1] + wsum[2] + wsum[3];
    atomicAdd(&totS[p], S);
    const float gf = (float)gnum;
    const float d = __fsub_rn(gf, expn_f);
    const float imb = __fdiv_rn(__fmul_rn(d, d), expn_f);
    atomicAdd(&accA[p * 4 + b], (double)imb / (double)gf);
  }
}

// ---------------------------------------------------------------------------
// Kernel 3: loss[b] = (1/5) * sum_p totS[p] * (accA[p][b] / 409)
// ---------------------------------------------------------------------------
__global__ void finalize_kernel(const double* __restrict__ totS,
                                const double* __restrict__ accA,
                                float* __restrict__ out) {
  const int b = threadIdx.x;
  if (b < B_SZ) {
    double acc = 0.0;
    for (int p = 0; p < 5; ++p)
      acc += totS[p] * (accA[p * 4 + b] / (double)SEED_NUM);
    out[b] = (float)(acc / 5.0);
  }
}

__global__ void zero_kernel(double* __restrict__ ptr) {
  const int t = threadIdx.x;
  if (t < 25) ptr[t] = 0.0;  // totS[5] + accA[20]
}

extern "C" void kernel_launch(void* const* d_in, const int* in_sizes, int n_in,
                              void* d_out, int out_size, void* d_ws,
                              size_t ws_size, hipStream_t stream) {
  (void)in_sizes; (void)n_in; (void)out_size; (void)ws_size;
  const float* pcs = (const float*)d_in[0];
  float* out = (float*)d_out;

  // ws layout: seeds (B*409*3 f32 = 19632 B, 8-aligned), then 25 doubles.
  float* seeds = (float*)d_ws;
  double* sums = (double*)((char*)d_ws + 19632);

  zero_kernel<<<1, 32, 0, stream>>>(sums);
  fps_kernel<<<B_SZ, FPS_THREADS, 0, stream>>>(pcs, seeds);
  dim3 grid(B_SZ * SEED_NUM, 5);
  group_kernel<<<grid, 256, 0, stream>>>(pcs, seeds, sums, sums + 5);
  finalize_kernel<<<1, 64, 0, stream>>>(sums, sums + 5, out);
}